// Round 9
// baseline (556.010 us; speedup 1.0000x reference)
//
#include <hip/hip_runtime.h>
#include <math.h>

#define H_  192
#define W_  192
#define HW_ (192 * 192)
#define B_  2
#define C_  64
#define PW_ 194            // padded width/height (1-px zero border)

typedef __attribute__((ext_vector_type(8))) short short8;
typedef __attribute__((ext_vector_type(4))) short short4v;
typedef __attribute__((ext_vector_type(4))) float float4v;
typedef _Float16 __attribute__((ext_vector_type(8))) half8;

// ---------------------------------------------------------------------------
// f16 2-limb split: x = h + l * 2^-12 ; l pre-scaled by 4096 (stays normal).
// ---------------------------------------------------------------------------
union hbits { _Float16 f; short s; };
__device__ __forceinline__ void split2(float x, short& h, short& l) {
    _Float16 hf = (_Float16)x;
    float r = (x - (float)hf) * 4096.f;
    _Float16 lf = (_Float16)r;
    hbits u;
    u.f = hf; h = u.s;
    u.f = lf; l = u.s;
}

// ---------------------------------------------------------------------------
// bilinear sample helpers on NHWC fp32 planes ([HW][64] one batch).
// ---------------------------------------------------------------------------
__device__ __forceinline__ float bilin_dot(const float* __restrict__ pl,
                                           float ys, float xs, int c4,
                                           float4v q4) {
    float y0 = floorf(ys), x0 = floorf(xs);
    float fy = ys - y0, fx = xs - x0;
    int iy = (int)y0, ix = (int)x0;
    float acc = 0.f;
    #pragma unroll
    for (int dy = 0; dy < 2; ++dy) {
        #pragma unroll
        for (int dx = 0; dx < 2; ++dx) {
            int yy = iy + dy, xx = ix + dx;
            float wgt = (dy ? fy : 1.f - fy) * (dx ? fx : 1.f - fx);
            bool valid = (yy >= 0) && (yy < H_) && (xx >= 0) && (xx < W_);
            int yc = min(max(yy, 0), H_ - 1);
            int xc = min(max(xx, 0), W_ - 1);
            const float4v v = *(const float4v*)(pl + (size_t)(yc * W_ + xc) * 64 + c4);
            float d = v[0] * q4[0] + v[1] * q4[1] + v[2] * q4[2] + v[3] * q4[3];
            acc += valid ? wgt * d : 0.f;
        }
    }
    return acc;
}
__device__ __forceinline__ float4v bilin_v4(const float* __restrict__ pl,
                                            float ys, float xs, int c4) {
    float y0 = floorf(ys), x0 = floorf(xs);
    float fy = ys - y0, fx = xs - x0;
    int iy = (int)y0, ix = (int)x0;
    float4v acc;
    acc[0] = acc[1] = acc[2] = acc[3] = 0.f;
    #pragma unroll
    for (int dy = 0; dy < 2; ++dy) {
        #pragma unroll
        for (int dx = 0; dx < 2; ++dx) {
            int yy = iy + dy, xx = ix + dx;
            float wgt = (dy ? fy : 1.f - fy) * (dx ? fx : 1.f - fx);
            bool valid = (yy >= 0) && (yy < H_) && (xx >= 0) && (xx < W_);
            float wz = valid ? wgt : 0.f;
            int yc = min(max(yy, 0), H_ - 1);
            int xc = min(max(xx, 0), W_ - 1);
            const float4v v = *(const float4v*)(pl + (size_t)(yc * W_ + xc) * 64 + c4);
            #pragma unroll
            for (int r = 0; r < 4; ++r) acc[r] += wz * v[r];
        }
    }
    return acc;
}

// ---------------------------------------------------------------------------
// weight pack: OIHW fp32 -> MFMA-fragment-ordered f16 2-limb. (unchanged)
// ---------------------------------------------------------------------------
__global__ __launch_bounds__(256) void prep_w_k(
    const float* __restrict__ w1, const float* __restrict__ w2,
    const float* __restrict__ wom,
    short* __restrict__ pw1, short* __restrict__ pw2, short* __restrict__ pwom)
{
    int idx = blockIdx.x * 256 + threadIdx.x;
    int arr;
    if (idx < 144 * 512) { arr = 0; }
    else if (idx < (144 + 72) * 512) { arr = 1; idx -= 144 * 512; }
    else if (idx < (144 + 72 + 252) * 512) { arr = 2; idx -= (144 + 72) * 512; }
    else return;
    int frag = idx >> 9, within = idx & 511;
    int lane = within >> 3, j = within & 7;
    int KS   = (arr == 0) ? 4 : 2;
    int mt   = frag / (9 * KS);
    int rem  = frag % (9 * KS);
    int kk   = rem / KS;
    int s    = rem % KS;
    int co   = mt * 16 + (lane & 15);
    int c    = s * 32 + (lane >> 4) * 8 + j;
    float v = 0.f;
    if (arr == 0)      v = w1[(co * 128 + c) * 9 + kk];
    else if (arr == 1) v = w2[(co * 64 + c) * 9 + kk];
    else if (co < 216) v = wom[(co * 64 + c) * 9 + kk];
    short h, l;
    split2(v, h, l);
    short* dst = (arr == 0) ? pw1 : (arr == 1) ? pw2 : pwom;
    size_t base = (size_t)frag * 1024 + lane * 8 + j;
    dst[base]       = h;
    dst[base + 512] = l;
}

// ---------------------------------------------------------------------------
// pack query+key -> padded f16 2-limb NHWC [b][194][194][h:128|l:128].
// XCD-aligned grid (same flat&7 band swizzle as conv_direct).
// ---------------------------------------------------------------------------
__global__ __launch_bounds__(256) void pack_qk(
    const float* __restrict__ q, const float* __restrict__ k,
    short* __restrict__ qk2)
{
    __shared__ float sm[128][65];
    const int tid  = threadIdx.x;
    const int flat = blockIdx.x;           // 1152 = 8 xcd * 144
    const int xcd  = flat & 7;
    const int cc_  = flat >> 3;
    const int b    = xcd >> 2;
    const int r4   = xcd & 3;
    const int i    = r4 * 48 + cc_ / 3;    // row, same band map as conv_direct
    const int j0   = (cc_ % 3) * 64;
    const int p0   = i * W_ + j0;
    const int pp   = tid & 63;
    const int r0   = tid >> 6;
    #pragma unroll
    for (int c = r0; c < 128; c += 4) {
        const float* src = (c < 64) ? q : k;
        sm[c][pp] = src[(size_t)(b * 64 + (c & 63)) * HW_ + p0 + pp];
    }
    __syncthreads();
    for (int idx = tid; idx < 64 * 128; idx += 256) {
        int pxw = idx >> 7, ci = idx & 127;
        short h, l;
        split2(sm[ci][pxw], h, l);
        short* dstp = qk2 + ((size_t)(b * PW_ + i + 1) * PW_ + j0 + pxw + 1) * 256;
        dstp[ci]       = h;
        dstp[128 + ci] = l;
    }
}

// ---------------------------------------------------------------------------
// zero the 1-px borders of the padded buffers. z: 0=f1p 1=f2p 2=qk2
// ---------------------------------------------------------------------------
__global__ __launch_bounds__(256) void zero_borders(
    short* __restrict__ f1p, short* __restrict__ f2p, short* __restrict__ qk2)
{
    const int prow = blockIdx.x;           // 0..193
    const int b    = blockIdx.y;
    const int z    = blockIdx.z;
    short* dst = (z == 0) ? f1p : (z == 1) ? f2p : qk2;
    const int nc = (z == 2) ? 256 : 128;
    dst += (size_t)(b * PW_ + prow) * PW_ * nc;
    if (prow == 0 || prow == PW_ - 1) {
        for (int idx = threadIdx.x; idx < PW_ * nc; idx += 256) dst[idx] = 0;
    } else {
        for (int idx = threadIdx.x; idx < nc; idx += 256) {
            dst[idx] = 0;                                  // pcol 0
            dst[(size_t)(PW_ - 1) * nc + idx] = 0;         // pcol 193
        }
    }
}

// ---------------------------------------------------------------------------
// NCHW -> NHWC fp32 transpose for key/value (sampler inputs)
// ---------------------------------------------------------------------------
__global__ __launch_bounds__(256) void nchw_to_nhwc(
    const float* __restrict__ key, const float* __restrict__ value,
    float* __restrict__ kT, float* __restrict__ vT)
{
    __shared__ float sm[64][65];
    const int tid = threadIdx.x;
    const int p0  = blockIdx.x * 64;
    const int b   = blockIdx.y;
    const float* src = blockIdx.z ? value : key;
    float*       dst = blockIdx.z ? vT    : kT;
    const int pp = tid & 63;
    const int r0 = tid >> 6;
    #pragma unroll
    for (int c = r0; c < 64; c += 4)
        sm[c][pp] = src[(size_t)(b * 64 + c) * HW_ + p0 + pp];
    __syncthreads();
    const int cc = tid & 63;
    #pragma unroll
    for (int pw = r0; pw < 64; pw += 4)
        dst[((size_t)b * HW_ + p0 + pw) * 64 + cc] = sm[cc][pw];
}

// ---------------------------------------------------------------------------
// v9: barrier-free direct-global conv, wave = ALL M-tiles x ONE 16-px
// N-subtile (wn = w). All 4 waves of a block stream IDENTICAL A-fragment
// addresses in identical order -> wave 0 misses L2, waves 1-3 hit L1
// (per-tap A set = MT*2KB <= 28KB < 32KB L1). B-regs halve (one subtile,
// one-tap-ahead ping-pong). __launch_bounds__(256,4) caps VGPR at 128
// -> 4 waves/SIMD (round-8's 132 VGPR dropped to 3).
// ---------------------------------------------------------------------------
template<int CIN, int MT, bool LRELU, int OUTMODE>
__global__ __launch_bounds__(256, 4) void conv_direct(
    const short* __restrict__ in, const short* __restrict__ pw,
    const float* __restrict__ bias, void* __restrict__ outv)
{
    constexpr int KS = CIN / 32;
    constexpr int NT = 9 * KS;             // flat taps: it -> (ky,kx,s)

    const int tid  = threadIdx.x;
    const int lane = tid & 63;
    const int wn   = tid >> 6;             // N-subtile (16 px) per wave
    const int quad = lane >> 4;
    const int nn   = lane & 15;

    // XCD-affine swizzle (1152 blocks = 8 xcd * 144)
    const int flat = blockIdx.x;
    const int xcd  = flat & 7;
    const int cc_  = flat >> 3;
    const int b    = xcd >> 2;
    const int r4   = xcd & 3;
    const int i    = r4 * 48 + cc_ / 3;    // output row
    const int j0   = (cc_ % 3) * 64;

    constexpr float CSC = 1.f / 4096.f;

    float4v accM[MT];
    #pragma unroll
    for (int m = 0; m < MT; ++m)
        #pragma unroll
        for (int r = 0; r < 4; ++r) accM[m][r] = 0.f;

    float4v zvec;
    zvec[0] = zvec[1] = zvec[2] = zvec[3] = 0.f;

    // B address for tap it (constant-folds under full unroll)
    auto baddr = [&](int it) -> const short* {
        const int ky = it / (3 * KS);
        const int rm = it % (3 * KS);
        const int kx = rm / KS;
        const int s  = rm % KS;
        const int pcol = j0 + kx + wn * 16 + nn;
        return in + ((size_t)(b * PW_ + i + ky) * PW_ + pcol) * (2 * CIN)
                  + s * 32 + quad * 8;
    };

    half8 bhc, blc;
    {
        const short* bp = baddr(0);
        bhc = *(const half8*)bp;
        blc = *(const half8*)(bp + CIN);
    }

    #pragma unroll
    for (int it = 0; it < NT; ++it) {
        half8 bhn, bln;
        if (it + 1 < NT) {
            const short* bp = baddr(it + 1);
            bhn = *(const half8*)bp;
            bln = *(const half8*)(bp + CIN);
        } else { bhn = bhc; bln = blc; }

        const int ky = it / (3 * KS);
        const int rm = it % (3 * KS);
        const int kx = rm / KS;
        const int s  = rm % KS;
        const int kk = ky * 3 + kx;

        #pragma unroll
        for (int m = 0; m < MT; ++m) {
            const short* ap = pw
                + ((size_t)((m * 9 + kk) * KS + s)) * 1024
                + lane * 8;
            half8 ah = *(const half8*)ap;
            half8 al = *(const half8*)(ap + 512);
            float4v t0;
            accM[m] = __builtin_amdgcn_mfma_f32_16x16x32_f16(ah, bhc, accM[m], 0, 0, 0);
            t0      = __builtin_amdgcn_mfma_f32_16x16x32_f16(ah, blc, zvec,    0, 0, 0);
            t0      = __builtin_amdgcn_mfma_f32_16x16x32_f16(al, bhc, t0,      0, 0, 0);
            #pragma unroll
            for (int r = 0; r < 4; ++r) accM[m][r] += t0[r] * CSC;
        }

        bhc = bhn; blc = bln;
    }

    // epilogue: C/D layout col(=px)=lane&15, row(=co)=quad*4+reg
    #pragma unroll
    for (int m = 0; m < MT; ++m) {
        const int co0 = m * 16 + quad * 4;
        if (OUTMODE == 0) {
            const size_t pp = ((size_t)(b * PW_ + i + 1) * PW_
                               + (j0 + wn * 16 + nn + 1)) * 128;
            short* feat = (short*)outv;
            short4v hv, lv;
            #pragma unroll
            for (int r = 0; r < 4; ++r) {
                float x = accM[m][r] + bias[co0 + r];
                if (LRELU) x = (x >= 0.f) ? x : 0.1f * x;
                short h, l;
                split2(x, h, l);
                hv[r] = h; lv[r] = l;
            }
            *(short4v*)(feat + pp + co0)      = hv;
            *(short4v*)(feat + pp + 64 + co0) = lv;
        } else {
            if (co0 < 216) {
                const int p = i * W_ + j0 + wn * 16 + nn;
                float* om = (float*)outv;
                float4v v;
                #pragma unroll
                for (int r = 0; r < 4; ++r)
                    v[r] = accM[m][r] + bias[co0 + r];
                *(float4v*)(om + ((size_t)b * HW_ + p) * 216 + co0) = v;
            }
        }
    }
}

// ---------------------------------------------------------------------------
// fused deformable sampling + top-2 attention. (unchanged)
// ---------------------------------------------------------------------------
__global__ __launch_bounds__(256) void sampler_k(
    const float* __restrict__ query, const float* __restrict__ kT,
    const float* __restrict__ vT, const float* __restrict__ om,
    float* __restrict__ out_w, float* __restrict__ out_v)
{
    __shared__ float sq[16 * 68];
    const int tid  = threadIdx.x;
    const int bb   = blockIdx.x;
    const int b    = bb / 2304;
    const int pblk = (bb - b * 2304) * 16;

    #pragma unroll
    for (int k = 0; k < 4; ++k) {
        int idx = tid + k * 256;
        int c   = idx >> 4;
        int px  = idx & 15;
        sq[px * 68 + c] = query[(size_t)(b * 64 + c) * HW_ + pblk + px];
    }
    __syncthreads();

    const int lane   = tid & 63;
    const int w      = tid >> 6;
    const int px_sub = lane >> 4;
    const int cl     = lane & 15;
    const int c4     = cl * 4;
    const int g      = cl >> 1;
    const int p      = pblk + w * 4 + px_sub;
    const int i      = p / W_;
    const int j      = p - i * W_;

    const float4v q4 = *(const float4v*)&sq[(w * 4 + px_sub) * 68 + c4];

    const float* omb = om + ((size_t)b * HW_ + p) * 216;
    float offy[9], offx[9], mk[9];
    #pragma unroll
    for (int n = 0; n < 9; ++n) {
        offy[n] = omb[g * 9 + n];
        offx[n] = omb[72 + g * 9 + n];
        float mv = omb[144 + g * 9 + n];
        mk[n] = 1.f / (1.f + expf(-mv));
    }

    const float* kpl = kT + (size_t)b * HW_ * 64;
    float rel[9];
    #pragma unroll
    for (int n = 0; n < 9; ++n) {
        float ys = (float)i + (float)(n / 3 - 1) + offy[n];
        float xs = (float)j + (float)(n % 3 - 1) + offx[n];
        float d = bilin_dot(kpl, ys, xs, c4, q4) * mk[n];
        #pragma unroll
        for (int off = 1; off < 16; off <<= 1)
            d += __shfl_xor(d, off, 64);
        rel[n] = d;
    }

    // top-2 with lax.top_k tie semantics (first occurrence of max wins)
    int n0 = 0; float v0 = rel[0];
    #pragma unroll
    for (int n = 1; n < 9; ++n) { if (rel[n] > v0) { v0 = rel[n]; n0 = n; } }
    int n1 = -1; float v1 = -1e30f;
    #pragma unroll
    for (int n = 0; n < 9; ++n) { if (n != n0 && rel[n] > v1) { v1 = rel[n]; n1 = n; } }

    float e1  = expf(v1 - v0);
    float inv = 1.f / (1.f + e1);
    float c0 = inv, c1 = e1 * inv;

    if (cl == 0) out_w[(size_t)b * HW_ + p] = c0 * v0 + c1 * v1;

    float oy0 = 0, ox0 = 0, m0 = 0, oy1 = 0, ox1 = 0, m1 = 0;
    #pragma unroll
    for (int n = 0; n < 9; ++n) {
        if (n == n0) { oy0 = offy[n]; ox0 = offx[n]; m0 = mk[n]; }
        if (n == n1) { oy1 = offy[n]; ox1 = offx[n]; m1 = mk[n]; }
    }

    const float* vpl = vT + (size_t)b * HW_ * 64;
    float ys0 = (float)i + (float)(n0 / 3 - 1) + oy0;
    float xs0 = (float)j + (float)(n0 % 3 - 1) + ox0;
    float ys1 = (float)i + (float)(n1 / 3 - 1) + oy1;
    float xs1 = (float)j + (float)(n1 % 3 - 1) + ox1;
    float4v vv0 = bilin_v4(vpl, ys0, xs0, c4);
    float4v vv1 = bilin_v4(vpl, ys1, xs1, c4);
    float w0 = c0 * m0, w1s = c1 * m1;
    #pragma unroll
    for (int r = 0; r < 4; ++r)
        out_v[(size_t)(b * C_ + c4 + r) * HW_ + p] = w0 * vv0[r] + w1s * vv1[r];
}

// ---------------------------------------------------------------------------
extern "C" void kernel_launch(void* const* d_in, const int* in_sizes, int n_in,
                              void* d_out, int out_size, void* d_ws, size_t ws_size,
                              hipStream_t stream)
{
    const float* query = (const float*)d_in[0];
    const float* key   = (const float*)d_in[1];
    const float* value = (const float*)d_in[2];
    const float* w1    = (const float*)d_in[3];
    const float* b1    = (const float*)d_in[4];
    const float* w2    = (const float*)d_in[5];
    const float* b2    = (const float*)d_in[6];
    const float* wom   = (const float*)d_in[7];
    const float* bom   = (const float*)d_in[8];
    float* out = (float*)d_out;

    // Liveness-packed workspace, cap 101,449,728 B (= om + kT + vT at s7).
    char* ws = (char*)d_ws;
    float* om   = (float*)(ws);
    short* f1p  = (short*)(ws);
    short* qk2  = (short*)(ws + 19269632);
    short* pw1  = (short*)(ws + 57808896);
    short* pw2  = (short*)(ws + 58103808);
    short* f2p  = (short*)(ws + 63700992);
    short* pwom = (short*)(ws + 82970624);
    float* kT   = (float*)(ws + 63700992);
    float* vT   = (float*)(ws + 82575360);

    zero_borders<<<dim3(PW_, B_, 3), 256, 0, stream>>>(f1p, f2p, qk2);
    pack_qk<<<1152, 256, 0, stream>>>(query, key, qk2);
    prep_w_k<<<936, 256, 0, stream>>>(w1, w2, wom, pw1, pw2, pwom);

    conv_direct<128, 4,  true,  0><<<1152, 256, 0, stream>>>(qk2, pw1, b1, (void*)f1p);
    conv_direct<64,  4,  true,  0><<<1152, 256, 0, stream>>>(f1p, pw2, b2, (void*)f2p);
    conv_direct<64,  14, false, 1><<<1152, 256, 0, stream>>>(f2p, pwom, bom, (void*)om);

    nchw_to_nhwc<<<dim3(576, B_, 2), 256, 0, stream>>>(key, value, kT, vT);

    float* out_w = out;
    float* out_v = out + (size_t)B_ * HW_;
    sampler_k<<<(B_ * HW_) / 16, 256, 0, stream>>>(query, kT, vT, om, out_w, out_v);
}

// Round 10
// 424.288 us; speedup vs baseline: 1.3105x; 1.3105x over previous
//
#include <hip/hip_runtime.h>
#include <math.h>

#define H_  192
#define W_  192
#define HW_ (192 * 192)
#define B_  2
#define C_  64

typedef __attribute__((ext_vector_type(8))) short short8;
typedef __attribute__((ext_vector_type(4))) short short4v;
typedef __attribute__((ext_vector_type(4))) float float4v;
typedef _Float16 __attribute__((ext_vector_type(8))) half8;

// ---------------------------------------------------------------------------
// f16 2-limb split: x = h + l * 2^-12 ; l pre-scaled by 4096 (stays normal).
// ---------------------------------------------------------------------------
union hbits { _Float16 f; short s; };
__device__ __forceinline__ void split2(float x, short& h, short& l) {
    _Float16 hf = (_Float16)x;
    float r = (x - (float)hf) * 4096.f;
    _Float16 lf = (_Float16)r;
    hbits u;
    u.f = hf; h = u.s;
    u.f = lf; l = u.s;
}

// ---------------------------------------------------------------------------
// bilinear sample helpers on NHWC fp32 planes ([HW][64] one batch).
// ---------------------------------------------------------------------------
__device__ __forceinline__ float bilin_dot(const float* __restrict__ pl,
                                           float ys, float xs, int c4,
                                           float4v q4) {
    float y0 = floorf(ys), x0 = floorf(xs);
    float fy = ys - y0, fx = xs - x0;
    int iy = (int)y0, ix = (int)x0;
    float acc = 0.f;
    #pragma unroll
    for (int dy = 0; dy < 2; ++dy) {
        #pragma unroll
        for (int dx = 0; dx < 2; ++dx) {
            int yy = iy + dy, xx = ix + dx;
            float wgt = (dy ? fy : 1.f - fy) * (dx ? fx : 1.f - fx);
            bool valid = (yy >= 0) && (yy < H_) && (xx >= 0) && (xx < W_);
            int yc = min(max(yy, 0), H_ - 1);
            int xc = min(max(xx, 0), W_ - 1);
            const float4v v = *(const float4v*)(pl + (size_t)(yc * W_ + xc) * 64 + c4);
            float d = v[0] * q4[0] + v[1] * q4[1] + v[2] * q4[2] + v[3] * q4[3];
            acc += valid ? wgt * d : 0.f;
        }
    }
    return acc;
}
__device__ __forceinline__ float4v bilin_v4(const float* __restrict__ pl,
                                            float ys, float xs, int c4) {
    float y0 = floorf(ys), x0 = floorf(xs);
    float fy = ys - y0, fx = xs - x0;
    int iy = (int)y0, ix = (int)x0;
    float4v acc;
    acc[0] = acc[1] = acc[2] = acc[3] = 0.f;
    #pragma unroll
    for (int dy = 0; dy < 2; ++dy) {
        #pragma unroll
        for (int dx = 0; dx < 2; ++dx) {
            int yy = iy + dy, xx = ix + dx;
            float wgt = (dy ? fy : 1.f - fy) * (dx ? fx : 1.f - fx);
            bool valid = (yy >= 0) && (yy < H_) && (xx >= 0) && (xx < W_);
            float wz = valid ? wgt : 0.f;
            int yc = min(max(yy, 0), H_ - 1);
            int xc = min(max(xx, 0), W_ - 1);
            const float4v v = *(const float4v*)(pl + (size_t)(yc * W_ + xc) * 64 + c4);
            #pragma unroll
            for (int r = 0; r < 4; ++r) acc[r] += wz * v[r];
        }
    }
    return acc;
}

// ---------------------------------------------------------------------------
// weight pack: OIHW fp32 -> MFMA-fragment-ordered f16 2-limb. (round-4)
// ---------------------------------------------------------------------------
__global__ __launch_bounds__(256) void prep_w_k(
    const float* __restrict__ w1, const float* __restrict__ w2,
    const float* __restrict__ wom,
    short* __restrict__ pw1, short* __restrict__ pw2, short* __restrict__ pwom)
{
    int idx = blockIdx.x * 256 + threadIdx.x;
    int arr;
    if (idx < 144 * 512) { arr = 0; }
    else if (idx < (144 + 72) * 512) { arr = 1; idx -= 144 * 512; }
    else if (idx < (144 + 72 + 252) * 512) { arr = 2; idx -= (144 + 72) * 512; }
    else return;
    int frag = idx >> 9, within = idx & 511;
    int lane = within >> 3, j = within & 7;
    int KS   = (arr == 0) ? 4 : 2;
    int mt   = frag / (9 * KS);
    int rem  = frag % (9 * KS);
    int kk   = rem / KS;
    int s    = rem % KS;
    int co   = mt * 16 + (lane & 15);
    int c    = s * 32 + (lane >> 4) * 8 + j;
    float v = 0.f;
    if (arr == 0)      v = w1[(co * 128 + c) * 9 + kk];
    else if (arr == 1) v = w2[(co * 64 + c) * 9 + kk];
    else if (co < 216) v = wom[(co * 64 + c) * 9 + kk];
    short h, l;
    split2(v, h, l);
    short* dst = (arr == 0) ? pw1 : (arr == 1) ? pw2 : pwom;
    size_t base = (size_t)frag * 1024 + lane * 8 + j;
    dst[base]       = h;
    dst[base + 512] = l;
}

// ---------------------------------------------------------------------------
// NCHW -> NHWC fp32 transpose for key/value (sampler inputs)
// ---------------------------------------------------------------------------
__global__ __launch_bounds__(256) void nchw_to_nhwc(
    const float* __restrict__ key, const float* __restrict__ value,
    float* __restrict__ kT, float* __restrict__ vT)
{
    __shared__ float sm[64][65];
    const int tid = threadIdx.x;
    const int p0  = blockIdx.x * 64;
    const int b   = blockIdx.y;
    const float* src = blockIdx.z ? value : key;
    float*       dst = blockIdx.z ? vT    : kT;
    const int pp = tid & 63;
    const int r0 = tid >> 6;
    #pragma unroll
    for (int c = r0; c < 64; c += 4)
        sm[c][pp] = src[(size_t)(b * 64 + c) * HW_ + p0 + pp];
    __syncthreads();
    const int cc = tid & 63;
    #pragma unroll
    for (int pw = r0; pw < 64; pw += 4)
        dst[((size_t)b * HW_ + p0 + pw) * 64 + cc] = sm[cc][pw];
}

// ---------------------------------------------------------------------------
// implicit-GEMM 3x3 SAME conv via mfma_f32_16x16x32_f16, 2-limb / 3-pass.
// EXACT round-4 structure (benched 429.8 total): stage->barrier->MFMA->barrier
// per (ky,s); transient cross-term fold keeps VGPR at 56.
// Only change: OUTMODE 1 epilogue applies sigmoid to mask channels (>=144)
// so the sampler reads ready-made masks (identical math, computed once).
// ---------------------------------------------------------------------------
template<int CIN, int MT, bool LRELU, int OUTMODE, bool FROMF32>
__global__ __launch_bounds__(256) void conv_mfma(
    const void* __restrict__ in0v, const void* __restrict__ in1v,
    const short* __restrict__ pw, const float* __restrict__ bias,
    void* __restrict__ outv)
{
    constexpr int KS   = CIN / 32;
    constexpr int MTW  = MT / 2;               // M-tiles per wave
    constexpr int LSTR = 72;                   // shorts per px: 2*32 + 8 pad
    __shared__ __align__(16) short smem[66 * LSTR];

    const int tid  = threadIdx.x;
    const int lane = tid & 63;
    const int w    = tid >> 6;                 // 0..3
    const int wh   = w & 1;                    // M-half
    const int wn   = w >> 1;                   // N-half
    const int quad = lane >> 4;
    const int nn   = lane & 15;

    // XCD-affine swizzle (1152 blocks = 8 xcd * 144)
    const int flat = blockIdx.x;
    const int xcd  = flat & 7;
    const int cc_  = flat >> 3;                // 0..143
    const int b    = xcd >> 2;                 // batch
    const int r4   = xcd & 3;
    const int i    = r4 * 48 + cc_ / 3;        // row
    const int j0   = (cc_ % 3) * 64;
    const int mt0  = wh * MTW;

    constexpr float CSC = 1.f / 4096.f;

    float4v accM[MTW][2];
    #pragma unroll
    for (int m = 0; m < MTW; ++m)
        #pragma unroll
        for (int t = 0; t < 2; ++t)
            #pragma unroll
            for (int r = 0; r < 4; ++r) accM[m][t][r] = 0.f;

    float4v zvec;                              // persistent zero C-operand
    zvec[0] = zvec[1] = zvec[2] = zvec[3] = 0.f;

    for (int ky = 0; ky < 3; ++ky) {
        const int row = i + ky - 1;
        const bool rowok = (row >= 0) && (row < H_);
        for (int s = 0; s < KS; ++s) {
            __syncthreads();
            if (FROMF32) {
                // conv1: src plane q (s<2) / k (s>=2), 32 fp32 ch -> 2 limbs
                const float* src = (s < KS / 2) ? (const float*)in0v
                                                : (const float*)in1v;
                const int cbase = (s & (KS / 2 - 1)) * 32;
                for (int idx = tid; idx < 32 * 66; idx += 256) {
                    int ci = idx / 66, px = idx - ci * 66;
                    int col = j0 - 1 + px;
                    float v = 0.f;
                    if (rowok && col >= 0 && col < W_)
                        v = src[(size_t)(b * 64 + cbase + ci) * HW_ + row * W_ + col];
                    short h, l;
                    split2(v, h, l);
                    smem[px * LSTR + ci]      = h;
                    smem[px * LSTR + 32 + ci] = l;
                }
            } else {
                // packed 2-limb feat [p][limb*CIN + ci], 8B chunks
                const short* src = (const short*)in0v
                                 + (size_t)b * HW_ * (2 * CIN);
                for (int idx = tid; idx < 66 * 16; idx += 256) {
                    int px = idx >> 4, r = idx & 15;
                    int limb = r >> 3, dq = r & 7;
                    int col = j0 - 1 + px;
                    unsigned long long v = 0;
                    if (rowok && col >= 0 && col < W_)
                        v = *(const unsigned long long*)(src
                              + (size_t)(row * W_ + col) * (2 * CIN)
                              + limb * CIN + s * 32 + dq * 4);
                    *(unsigned long long*)(&smem[px * LSTR + limb * 32 + dq * 4]) = v;
                }
            }
            __syncthreads();

            #pragma unroll
            for (int kx = 0; kx < 3; ++kx) {
                const int kk = ky * 3 + kx;
                half8 bh[2], bl[2];
                #pragma unroll
                for (int t2 = 0; t2 < 2; ++t2) {
                    const int t = wn * 2 + t2;
                    const short* bp = &smem[(t * 16 + nn + kx) * LSTR + quad * 8];
                    bh[t2] = *(const half8*)bp;
                    bl[t2] = *(const half8*)(bp + 32);
                }
                #pragma unroll
                for (int m = 0; m < MTW; ++m) {
                    const short* ap = pw
                        + ((size_t)(((mt0 + m) * 9 + kk) * KS + s)) * 1024
                        + lane * 8;
                    half8 ah = *(const half8*)ap;
                    half8 al = *(const half8*)(ap + 512);
                    // main terms (persistent acc) + transient cross terms
                    float4v t0, t1;
                    accM[m][0] = __builtin_amdgcn_mfma_f32_16x16x32_f16(ah, bh[0], accM[m][0], 0, 0, 0);
                    t0         = __builtin_amdgcn_mfma_f32_16x16x32_f16(ah, bl[0], zvec,       0, 0, 0);
                    accM[m][1] = __builtin_amdgcn_mfma_f32_16x16x32_f16(ah, bh[1], accM[m][1], 0, 0, 0);
                    t1         = __builtin_amdgcn_mfma_f32_16x16x32_f16(ah, bl[1], zvec,       0, 0, 0);
                    t0         = __builtin_amdgcn_mfma_f32_16x16x32_f16(al, bh[0], t0,         0, 0, 0);
                    t1         = __builtin_amdgcn_mfma_f32_16x16x32_f16(al, bh[1], t1,         0, 0, 0);
                    #pragma unroll
                    for (int r = 0; r < 4; ++r) {
                        accM[m][0][r] += t0[r] * CSC;
                        accM[m][1][r] += t1[r] * CSC;
                    }
                }
            }
        }
    }

    // epilogue: C/D layout col(=px)=lane&15, row(=co)=quad*4+reg (verified m89)
    #pragma unroll
    for (int m = 0; m < MTW; ++m) {
        const int co0 = (mt0 + m) * 16 + quad * 4;
        #pragma unroll
        for (int t2 = 0; t2 < 2; ++t2) {
            const int t = wn * 2 + t2;
            const int p = i * W_ + j0 + t * 16 + nn;
            if (OUTMODE == 0) {
                short* feat = (short*)outv;
                short4v hv, lv;
                #pragma unroll
                for (int r = 0; r < 4; ++r) {
                    float x = accM[m][t2][r] + bias[co0 + r];
                    if (LRELU) x = (x >= 0.f) ? x : 0.1f * x;
                    short h, l;
                    split2(x, h, l);
                    hv[r] = h; lv[r] = l;
                }
                short* dp = feat + ((size_t)b * HW_ + p) * 128 + co0;
                *(short4v*)dp        = hv;
                *(short4v*)(dp + 64) = lv;
            } else {
                if (co0 < 216) {
                    float* om = (float*)outv;
                    float4v v;
                    #pragma unroll
                    for (int r = 0; r < 4; ++r)
                        v[r] = accM[m][t2][r] + bias[co0 + r];
                    if (co0 >= 144) {
                        // mask channels: pre-apply sigmoid (same math the
                        // sampler used; computed once instead of 16x)
                        #pragma unroll
                        for (int r = 0; r < 4; ++r)
                            v[r] = 1.f / (1.f + expf(-v[r]));
                    }
                    *(float4v*)(om + ((size_t)b * HW_ + p) * 216 + co0) = v;
                }
            }
        }
    }
}

// ---------------------------------------------------------------------------
// fused deformable sampling + top-2 attention, v3.
// Changes vs v2: (1) om block (16 px x 216 ch) staged into LDS with
// coalesced float4 loads — replaces 27 scalar global loads PER LANE
// (432 scalar VMEM per px) with 4 vector VMEM per thread. (2) masks are
// pre-sigmoided by conv_om. (3) XCD-band-swizzled grid matching conv_om's
// write bands for om L2 locality.
// ---------------------------------------------------------------------------
__global__ __launch_bounds__(256) void sampler_k(
    const float* __restrict__ query, const float* __restrict__ kT,
    const float* __restrict__ vT, const float* __restrict__ om,
    float* __restrict__ out_w, float* __restrict__ out_v)
{
    __shared__ float sq[16 * 68];
    __shared__ float som[16 * 220];        // 216 ch + 4 pad
    const int tid  = threadIdx.x;
    // band swizzle: 4608 blocks = 8 xcd * 576 ; xcd -> (b, 48-row band)
    const int flat = blockIdx.x;
    const int xcd  = flat & 7;
    const int cc_  = flat >> 3;            // 0..575
    const int b    = xcd >> 2;
    const int r4   = xcd & 3;
    const int row  = r4 * 48 + cc_ / 12;
    const int pblk = row * W_ + (cc_ % 12) * 16;

    // stage q[16 px][64 ch] -> LDS (coalesced)
    #pragma unroll
    for (int k = 0; k < 4; ++k) {
        int idx = tid + k * 256;           // 0..1023
        int c   = idx >> 4;
        int px  = idx & 15;
        sq[px * 68 + c] = query[(size_t)(b * 64 + c) * HW_ + pblk + px];
    }
    // stage om[16 px][216] -> LDS, coalesced float4 (3456 floats = 864 x f4)
    {
        const float4v* omp = (const float4v*)(om + ((size_t)b * HW_ + pblk) * 216);
        for (int u = tid; u < 864; u += 256) {
            float4v v = omp[u];
            int px  = u / 54;              // 54 float4 per px
            int c4i = (u - px * 54) * 4;
            float* d = &som[px * 220 + c4i];
            d[0] = v[0]; d[1] = v[1]; d[2] = v[2]; d[3] = v[3];
        }
    }
    __syncthreads();

    const int lane   = tid & 63;
    const int w      = tid >> 6;
    const int px_sub = lane >> 4;
    const int cl     = lane & 15;
    const int c4     = cl * 4;
    const int g      = cl >> 1;
    const int pxl    = w * 4 + px_sub;     // 0..15 within block
    const int p      = pblk + pxl;
    const int i      = p / W_;
    const int j      = p - i * W_;

    const float4v q4 = *(const float4v*)&sq[pxl * 68 + c4];

    const float* somp = &som[pxl * 220];
    float offy[9], offx[9], mk[9];
    #pragma unroll
    for (int n = 0; n < 9; ++n) {
        offy[n] = somp[g * 9 + n];
        offx[n] = somp[72 + g * 9 + n];
        mk[n]   = somp[144 + g * 9 + n];   // sigmoid pre-applied by conv_om
    }

    const float* kpl = kT + (size_t)b * HW_ * 64;
    float rel[9];
    #pragma unroll
    for (int n = 0; n < 9; ++n) {
        float ys = (float)i + (float)(n / 3 - 1) + offy[n];
        float xs = (float)j + (float)(n % 3 - 1) + offx[n];
        float d = bilin_dot(kpl, ys, xs, c4, q4) * mk[n];
        #pragma unroll
        for (int off = 1; off < 16; off <<= 1)
            d += __shfl_xor(d, off, 64);
        rel[n] = d;
    }

    // top-2 with lax.top_k tie semantics (first occurrence of max wins)
    int n0 = 0; float v0 = rel[0];
    #pragma unroll
    for (int n = 1; n < 9; ++n) { if (rel[n] > v0) { v0 = rel[n]; n0 = n; } }
    int n1 = -1; float v1 = -1e30f;
    #pragma unroll
    for (int n = 0; n < 9; ++n) { if (n != n0 && rel[n] > v1) { v1 = rel[n]; n1 = n; } }

    float e1  = expf(v1 - v0);
    float inv = 1.f / (1.f + e1);
    float c0 = inv, c1 = e1 * inv;

    if (cl == 0) out_w[(size_t)b * HW_ + p] = c0 * v0 + c1 * v1;

    float oy0 = 0, ox0 = 0, m0 = 0, oy1 = 0, ox1 = 0, m1 = 0;
    #pragma unroll
    for (int n = 0; n < 9; ++n) {
        if (n == n0) { oy0 = offy[n]; ox0 = offx[n]; m0 = mk[n]; }
        if (n == n1) { oy1 = offy[n]; ox1 = offx[n]; m1 = mk[n]; }
    }

    const float* vpl = vT + (size_t)b * HW_ * 64;
    float ys0 = (float)i + (float)(n0 / 3 - 1) + oy0;
    float xs0 = (float)j + (float)(n0 % 3 - 1) + ox0;
    float ys1 = (float)i + (float)(n1 / 3 - 1) + oy1;
    float xs1 = (float)j + (float)(n1 % 3 - 1) + ox1;
    float4v vv0 = bilin_v4(vpl, ys0, xs0, c4);
    float4v vv1 = bilin_v4(vpl, ys1, xs1, c4);
    float w0 = c0 * m0, w1s = c1 * m1;
    #pragma unroll
    for (int r = 0; r < 4; ++r)
        out_v[(size_t)(b * C_ + c4 + r) * HW_ + p] = w0 * vv0[r] + w1s * vv1[r];
}

// ---------------------------------------------------------------------------
extern "C" void kernel_launch(void* const* d_in, const int* in_sizes, int n_in,
                              void* d_out, int out_size, void* d_ws, size_t ws_size,
                              hipStream_t stream)
{
    const float* query = (const float*)d_in[0];
    const float* key   = (const float*)d_in[1];
    const float* value = (const float*)d_in[2];
    const float* w1    = (const float*)d_in[3];
    const float* b1    = (const float*)d_in[4];
    const float* w2    = (const float*)d_in[5];
    const float* b2    = (const float*)d_in[6];
    const float* wom   = (const float*)d_in[7];
    const float* bom   = (const float*)d_in[8];
    float* out = (float*)d_out;

    // Round-4 liveness-packed workspace (proven): f16 2-limb arrays are
    // smaller than their original bf16 slots.
    char* ws = (char*)d_ws;
    short* f1  = (short*)(ws);
    float* om  = (float*)(ws);
    short* f2  = (short*)(ws + 63700992);
    float* kT  = (float*)(ws + 63700992);
    float* vT  = (float*)(ws + 82575360);
    short* pwom= (short*)(ws + 92012544);
    short* pw1 = (short*)(ws + 92786688);
    short* pw2 = (short*)(ws + 93229056);

    prep_w_k<<<936, 256, 0, stream>>>(w1, w2, wom, pw1, pw2, pwom);

    conv_mfma<128, 4,  true,  0, true ><<<1152, 256, 0, stream>>>(query, key, pw1, b1, (void*)f1);
    conv_mfma<64,  4,  true,  0, false><<<1152, 256, 0, stream>>>(f1, nullptr, pw2, b2, (void*)f2);
    conv_mfma<64,  14, false, 1, false><<<1152, 256, 0, stream>>>(f2, nullptr, pwom, bom, (void*)om);

    nchw_to_nhwc<<<dim3(576, B_, 2), 256, 0, stream>>>(key, value, kT, vT);

    float* out_w = out;
    float* out_v = out + (size_t)B_ * HW_;
    sampler_k<<<(B_ * HW_) / 16, 256, 0, stream>>>(query, kT, vT, om, out_w, out_v);
}

// Round 11
// 407.859 us; speedup vs baseline: 1.3632x; 1.0403x over previous
//
#include <hip/hip_runtime.h>
#include <math.h>

#define H_  192
#define W_  192
#define HW_ (192 * 192)
#define B_  2
#define C_  64

typedef __attribute__((ext_vector_type(8))) short short8;
typedef __attribute__((ext_vector_type(4))) short short4v;
typedef __attribute__((ext_vector_type(4))) float float4v;
typedef _Float16 __attribute__((ext_vector_type(8))) half8;

// ---------------------------------------------------------------------------
// f16 2-limb split: x = h + l * 2^-12 ; l pre-scaled by 4096 (stays normal).
// ---------------------------------------------------------------------------
union hbits { _Float16 f; short s; };
__device__ __forceinline__ void split2(float x, short& h, short& l) {
    _Float16 hf = (_Float16)x;
    float r = (x - (float)hf) * 4096.f;
    _Float16 lf = (_Float16)r;
    hbits u;
    u.f = hf; h = u.s;
    u.f = lf; l = u.s;
}

// ---------------------------------------------------------------------------
// bilinear sample helpers on NHWC fp32 planes ([HW][64] one batch).
// ---------------------------------------------------------------------------
__device__ __forceinline__ float bilin_dot(const float* __restrict__ pl,
                                           float ys, float xs, int c4,
                                           float4v q4) {
    float y0 = floorf(ys), x0 = floorf(xs);
    float fy = ys - y0, fx = xs - x0;
    int iy = (int)y0, ix = (int)x0;
    float acc = 0.f;
    #pragma unroll
    for (int dy = 0; dy < 2; ++dy) {
        #pragma unroll
        for (int dx = 0; dx < 2; ++dx) {
            int yy = iy + dy, xx = ix + dx;
            float wgt = (dy ? fy : 1.f - fy) * (dx ? fx : 1.f - fx);
            bool valid = (yy >= 0) && (yy < H_) && (xx >= 0) && (xx < W_);
            int yc = min(max(yy, 0), H_ - 1);
            int xc = min(max(xx, 0), W_ - 1);
            const float4v v = *(const float4v*)(pl + (size_t)(yc * W_ + xc) * 64 + c4);
            float d = v[0] * q4[0] + v[1] * q4[1] + v[2] * q4[2] + v[3] * q4[3];
            acc += valid ? wgt * d : 0.f;
        }
    }
    return acc;
}
__device__ __forceinline__ float4v bilin_v4(const float* __restrict__ pl,
                                            float ys, float xs, int c4) {
    float y0 = floorf(ys), x0 = floorf(xs);
    float fy = ys - y0, fx = xs - x0;
    int iy = (int)y0, ix = (int)x0;
    float4v acc;
    acc[0] = acc[1] = acc[2] = acc[3] = 0.f;
    #pragma unroll
    for (int dy = 0; dy < 2; ++dy) {
        #pragma unroll
        for (int dx = 0; dx < 2; ++dx) {
            int yy = iy + dy, xx = ix + dx;
            float wgt = (dy ? fy : 1.f - fy) * (dx ? fx : 1.f - fx);
            bool valid = (yy >= 0) && (yy < H_) && (xx >= 0) && (xx < W_);
            float wz = valid ? wgt : 0.f;
            int yc = min(max(yy, 0), H_ - 1);
            int xc = min(max(xx, 0), W_ - 1);
            const float4v v = *(const float4v*)(pl + (size_t)(yc * W_ + xc) * 64 + c4);
            #pragma unroll
            for (int r = 0; r < 4; ++r) acc[r] += wz * v[r];
        }
    }
    return acc;
}

// ---------------------------------------------------------------------------
// weight pack: OIHW fp32 -> MFMA-fragment-ordered f16 2-limb. (unchanged)
// ---------------------------------------------------------------------------
__global__ __launch_bounds__(256) void prep_w_k(
    const float* __restrict__ w1, const float* __restrict__ w2,
    const float* __restrict__ wom,
    short* __restrict__ pw1, short* __restrict__ pw2, short* __restrict__ pwom)
{
    int idx = blockIdx.x * 256 + threadIdx.x;
    int arr;
    if (idx < 144 * 512) { arr = 0; }
    else if (idx < (144 + 72) * 512) { arr = 1; idx -= 144 * 512; }
    else if (idx < (144 + 72 + 252) * 512) { arr = 2; idx -= (144 + 72) * 512; }
    else return;
    int frag = idx >> 9, within = idx & 511;
    int lane = within >> 3, j = within & 7;
    int KS   = (arr == 0) ? 4 : 2;
    int mt   = frag / (9 * KS);
    int rem  = frag % (9 * KS);
    int kk   = rem / KS;
    int s    = rem % KS;
    int co   = mt * 16 + (lane & 15);
    int c    = s * 32 + (lane >> 4) * 8 + j;
    float v = 0.f;
    if (arr == 0)      v = w1[(co * 128 + c) * 9 + kk];
    else if (arr == 1) v = w2[(co * 64 + c) * 9 + kk];
    else if (co < 216) v = wom[(co * 64 + c) * 9 + kk];
    short h, l;
    split2(v, h, l);
    short* dst = (arr == 0) ? pw1 : (arr == 1) ? pw2 : pwom;
    size_t base = (size_t)frag * 1024 + lane * 8 + j;
    dst[base]       = h;
    dst[base + 512] = l;
}

// ---------------------------------------------------------------------------
// NCHW -> NHWC fp32 transpose for key/value (sampler inputs)
// ---------------------------------------------------------------------------
__global__ __launch_bounds__(256) void nchw_to_nhwc(
    const float* __restrict__ key, const float* __restrict__ value,
    float* __restrict__ kT, float* __restrict__ vT)
{
    __shared__ float sm[64][65];
    const int tid = threadIdx.x;
    const int p0  = blockIdx.x * 64;
    const int b   = blockIdx.y;
    const float* src = blockIdx.z ? value : key;
    float*       dst = blockIdx.z ? vT    : kT;
    const int pp = tid & 63;
    const int r0 = tid >> 6;
    #pragma unroll
    for (int c = r0; c < 64; c += 4)
        sm[c][pp] = src[(size_t)(b * 64 + c) * HW_ + p0 + pp];
    __syncthreads();
    const int cc = tid & 63;
    #pragma unroll
    for (int pw = r0; pw < 64; pw += 4)
        dst[((size_t)b * HW_ + p0 + pw) * 64 + cc] = sm[cc][pw];
}

// ---------------------------------------------------------------------------
// implicit-GEMM 3x3 SAME conv via mfma_f32_16x16x32_f16, 2-limb / 3-pass.
// v11: round-4 schedule, but 32-px N-tile / 2304-block grid (9 blocks/CU vs
// 4.5). Round-10 counters showed occupancy was GRID-limited (VGPR 56,
// LDS 9.7KB but occ 27.9%): too few resident blocks to hide staging + A-load
// latency across barrier convoys. Halving the tile doubles resident blocks;
// each wave owns ONE 16-px subtile (acc t2-dim dropped -> fewer VGPRs).
// Per-output arithmetic order identical to round 4 -> bitwise same result.
// ---------------------------------------------------------------------------
template<int CIN, int MT, bool LRELU, int OUTMODE, bool FROMF32>
__global__ __launch_bounds__(256) void conv_mfma(
    const void* __restrict__ in0v, const void* __restrict__ in1v,
    const short* __restrict__ pw, const float* __restrict__ bias,
    void* __restrict__ outv)
{
    constexpr int KS   = CIN / 32;
    constexpr int MTW  = MT / 2;               // M-tiles per wave
    constexpr int LSTR = 72;                   // shorts per px: 2*32 + 8 pad
    __shared__ __align__(16) short smem[34 * LSTR];

    const int tid  = threadIdx.x;
    const int lane = tid & 63;
    const int w    = tid >> 6;                 // 0..3
    const int wh   = w & 1;                    // M-half
    const int wn   = w >> 1;                   // N-subtile (16 px)
    const int quad = lane >> 4;
    const int nn   = lane & 15;

    // XCD-affine swizzle (2304 blocks = 8 xcd * 288)
    const int flat = blockIdx.x;
    const int xcd  = flat & 7;
    const int cc_  = flat >> 3;                // 0..287
    const int b    = xcd >> 2;                 // batch
    const int r4   = xcd & 3;
    const int i    = r4 * 48 + cc_ / 6;        // row
    const int j0   = (cc_ % 6) * 32;
    const int mt0  = wh * MTW;

    constexpr float CSC = 1.f / 4096.f;

    float4v accM[MTW];
    #pragma unroll
    for (int m = 0; m < MTW; ++m)
        #pragma unroll
        for (int r = 0; r < 4; ++r) accM[m][r] = 0.f;

    float4v zvec;                              // persistent zero C-operand
    zvec[0] = zvec[1] = zvec[2] = zvec[3] = 0.f;

    for (int ky = 0; ky < 3; ++ky) {
        const int row = i + ky - 1;
        const bool rowok = (row >= 0) && (row < H_);
        for (int s = 0; s < KS; ++s) {
            __syncthreads();
            if (FROMF32) {
                // conv1: src plane q (s<2) / k (s>=2), 32 fp32 ch -> 2 limbs
                const float* src = (s < KS / 2) ? (const float*)in0v
                                                : (const float*)in1v;
                const int cbase = (s & (KS / 2 - 1)) * 32;
                for (int idx = tid; idx < 32 * 34; idx += 256) {
                    int ci = idx / 34, px = idx - ci * 34;
                    int col = j0 - 1 + px;
                    float v = 0.f;
                    if (rowok && col >= 0 && col < W_)
                        v = src[(size_t)(b * 64 + cbase + ci) * HW_ + row * W_ + col];
                    short h, l;
                    split2(v, h, l);
                    smem[px * LSTR + ci]      = h;
                    smem[px * LSTR + 32 + ci] = l;
                }
            } else {
                // packed 2-limb feat [p][limb*CIN + ci], 8B chunks
                const short* src = (const short*)in0v
                                 + (size_t)b * HW_ * (2 * CIN);
                for (int idx = tid; idx < 34 * 16; idx += 256) {
                    int px = idx >> 4, r = idx & 15;
                    int limb = r >> 3, dq = r & 7;
                    int col = j0 - 1 + px;
                    unsigned long long v = 0;
                    if (rowok && col >= 0 && col < W_)
                        v = *(const unsigned long long*)(src
                              + (size_t)(row * W_ + col) * (2 * CIN)
                              + limb * CIN + s * 32 + dq * 4);
                    *(unsigned long long*)(&smem[px * LSTR + limb * 32 + dq * 4]) = v;
                }
            }
            __syncthreads();

            #pragma unroll
            for (int kx = 0; kx < 3; ++kx) {
                const int kk = ky * 3 + kx;
                half8 bh, bl;
                {
                    const short* bp = &smem[(wn * 16 + nn + kx) * LSTR + quad * 8];
                    bh = *(const half8*)bp;
                    bl = *(const half8*)(bp + 32);
                }
                #pragma unroll
                for (int m = 0; m < MTW; ++m) {
                    const short* ap = pw
                        + ((size_t)(((mt0 + m) * 9 + kk) * KS + s)) * 1024
                        + lane * 8;
                    half8 ah = *(const half8*)ap;
                    half8 al = *(const half8*)(ap + 512);
                    // main term (persistent acc) + transient cross terms
                    float4v t0;
                    accM[m] = __builtin_amdgcn_mfma_f32_16x16x32_f16(ah, bh, accM[m], 0, 0, 0);
                    t0      = __builtin_amdgcn_mfma_f32_16x16x32_f16(ah, bl, zvec,    0, 0, 0);
                    t0      = __builtin_amdgcn_mfma_f32_16x16x32_f16(al, bh, t0,      0, 0, 0);
                    #pragma unroll
                    for (int r = 0; r < 4; ++r)
                        accM[m][r] += t0[r] * CSC;
                }
            }
        }
    }

    // epilogue: C/D layout col(=px)=lane&15, row(=co)=quad*4+reg (verified m89)
    #pragma unroll
    for (int m = 0; m < MTW; ++m) {
        const int co0 = (mt0 + m) * 16 + quad * 4;
        const int p = i * W_ + j0 + wn * 16 + nn;
        if (OUTMODE == 0) {
            short* feat = (short*)outv;
            short4v hv, lv;
            #pragma unroll
            for (int r = 0; r < 4; ++r) {
                float x = accM[m][r] + bias[co0 + r];
                if (LRELU) x = (x >= 0.f) ? x : 0.1f * x;
                short h, l;
                split2(x, h, l);
                hv[r] = h; lv[r] = l;
            }
            short* dp = feat + ((size_t)b * HW_ + p) * 128 + co0;
            *(short4v*)dp        = hv;
            *(short4v*)(dp + 64) = lv;
        } else {
            if (co0 < 216) {
                float* om = (float*)outv;
                float4v v;
                #pragma unroll
                for (int r = 0; r < 4; ++r)
                    v[r] = accM[m][r] + bias[co0 + r];
                if (co0 >= 144) {
                    // mask channels: pre-apply sigmoid (same math the
                    // sampler used; computed once instead of 16x)
                    #pragma unroll
                    for (int r = 0; r < 4; ++r)
                        v[r] = 1.f / (1.f + expf(-v[r]));
                }
                *(float4v*)(om + ((size_t)b * HW_ + p) * 216 + co0) = v;
            }
        }
    }
}

// ---------------------------------------------------------------------------
// fused deformable sampling + top-2 attention, v3 (round-10, unchanged):
// om block staged in LDS via coalesced float4; masks pre-sigmoided by
// conv_om; XCD-band-swizzled grid.
// ---------------------------------------------------------------------------
__global__ __launch_bounds__(256) void sampler_k(
    const float* __restrict__ query, const float* __restrict__ kT,
    const float* __restrict__ vT, const float* __restrict__ om,
    float* __restrict__ out_w, float* __restrict__ out_v)
{
    __shared__ float sq[16 * 68];
    __shared__ float som[16 * 220];        // 216 ch + 4 pad
    const int tid  = threadIdx.x;
    // band swizzle: 4608 blocks = 8 xcd * 576 ; xcd -> (b, 48-row band)
    const int flat = blockIdx.x;
    const int xcd  = flat & 7;
    const int cc_  = flat >> 3;            // 0..575
    const int b    = xcd >> 2;
    const int r4   = xcd & 3;
    const int row  = r4 * 48 + cc_ / 12;
    const int pblk = row * W_ + (cc_ % 12) * 16;

    // stage q[16 px][64 ch] -> LDS (coalesced)
    #pragma unroll
    for (int k = 0; k < 4; ++k) {
        int idx = tid + k * 256;           // 0..1023
        int c   = idx >> 4;
        int px  = idx & 15;
        sq[px * 68 + c] = query[(size_t)(b * 64 + c) * HW_ + pblk + px];
    }
    // stage om[16 px][216] -> LDS, coalesced float4 (3456 floats = 864 x f4)
    {
        const float4v* omp = (const float4v*)(om + ((size_t)b * HW_ + pblk) * 216);
        for (int u = tid; u < 864; u += 256) {
            float4v v = omp[u];
            int px  = u / 54;              // 54 float4 per px
            int c4i = (u - px * 54) * 4;
            float* d = &som[px * 220 + c4i];
            d[0] = v[0]; d[1] = v[1]; d[2] = v[2]; d[3] = v[3];
        }
    }
    __syncthreads();

    const int lane   = tid & 63;
    const int w      = tid >> 6;
    const int px_sub = lane >> 4;
    const int cl     = lane & 15;
    const int c4     = cl * 4;
    const int g      = cl >> 1;
    const int pxl    = w * 4 + px_sub;     // 0..15 within block
    const int p      = pblk + pxl;
    const int i      = p / W_;
    const int j      = p - i * W_;

    const float4v q4 = *(const float4v*)&sq[pxl * 68 + c4];

    const float* somp = &som[pxl * 220];
    float offy[9], offx[9], mk[9];
    #pragma unroll
    for (int n = 0; n < 9; ++n) {
        offy[n] = somp[g * 9 + n];
        offx[n] = somp[72 + g * 9 + n];
        mk[n]   = somp[144 + g * 9 + n];   // sigmoid pre-applied by conv_om
    }

    const float* kpl = kT + (size_t)b * HW_ * 64;
    float rel[9];
    #pragma unroll
    for (int n = 0; n < 9; ++n) {
        float ys = (float)i + (float)(n / 3 - 1) + offy[n];
        float xs = (float)j + (float)(n % 3 - 1) + offx[n];
        float d = bilin_dot(kpl, ys, xs, c4, q4) * mk[n];
        #pragma unroll
        for (int off = 1; off < 16; off <<= 1)
            d += __shfl_xor(d, off, 64);
        rel[n] = d;
    }

    // top-2 with lax.top_k tie semantics (first occurrence of max wins)
    int n0 = 0; float v0 = rel[0];
    #pragma unroll
    for (int n = 1; n < 9; ++n) { if (rel[n] > v0) { v0 = rel[n]; n0 = n; } }
    int n1 = -1; float v1 = -1e30f;
    #pragma unroll
    for (int n = 0; n < 9; ++n) { if (n != n0 && rel[n] > v1) { v1 = rel[n]; n1 = n; } }

    float e1  = expf(v1 - v0);
    float inv = 1.f / (1.f + e1);
    float c0 = inv, c1 = e1 * inv;

    if (cl == 0) out_w[(size_t)b * HW_ + p] = c0 * v0 + c1 * v1;

    float oy0 = 0, ox0 = 0, m0 = 0, oy1 = 0, ox1 = 0, m1 = 0;
    #pragma unroll
    for (int n = 0; n < 9; ++n) {
        if (n == n0) { oy0 = offy[n]; ox0 = offx[n]; m0 = mk[n]; }
        if (n == n1) { oy1 = offy[n]; ox1 = offx[n]; m1 = mk[n]; }
    }

    const float* vpl = vT + (size_t)b * HW_ * 64;
    float ys0 = (float)i + (float)(n0 / 3 - 1) + oy0;
    float xs0 = (float)j + (float)(n0 % 3 - 1) + ox0;
    float ys1 = (float)i + (float)(n1 / 3 - 1) + oy1;
    float xs1 = (float)j + (float)(n1 % 3 - 1) + ox1;
    float4v vv0 = bilin_v4(vpl, ys0, xs0, c4);
    float4v vv1 = bilin_v4(vpl, ys1, xs1, c4);
    float w0 = c0 * m0, w1s = c1 * m1;
    #pragma unroll
    for (int r = 0; r < 4; ++r)
        out_v[(size_t)(b * C_ + c4 + r) * HW_ + p] = w0 * vv0[r] + w1s * vv1[r];
}

// ---------------------------------------------------------------------------
extern "C" void kernel_launch(void* const* d_in, const int* in_sizes, int n_in,
                              void* d_out, int out_size, void* d_ws, size_t ws_size,
                              hipStream_t stream)
{
    const float* query = (const float*)d_in[0];
    const float* key   = (const float*)d_in[1];
    const float* value = (const float*)d_in[2];
    const float* w1    = (const float*)d_in[3];
    const float* b1    = (const float*)d_in[4];
    const float* w2    = (const float*)d_in[5];
    const float* b2    = (const float*)d_in[6];
    const float* wom   = (const float*)d_in[7];
    const float* bom   = (const float*)d_in[8];
    float* out = (float*)d_out;

    // Round-4 liveness-packed workspace (proven).
    char* ws = (char*)d_ws;
    short* f1  = (short*)(ws);
    float* om  = (float*)(ws);
    short* f2  = (short*)(ws + 63700992);
    float* kT  = (float*)(ws + 63700992);
    float* vT  = (float*)(ws + 82575360);
    short* pwom= (short*)(ws + 92012544);
    short* pw1 = (short*)(ws + 92786688);
    short* pw2 = (short*)(ws + 93229056);

    prep_w_k<<<936, 256, 0, stream>>>(w1, w2, wom, pw1, pw2, pwom);

    conv_mfma<128, 4,  true,  0, true ><<<2304, 256, 0, stream>>>(query, key, pw1, b1, (void*)f1);
    conv_mfma<64,  4,  true,  0, false><<<2304, 256, 0, stream>>>(f1, nullptr, pw2, b2, (void*)f2);
    conv_mfma<64,  14, false, 1, false><<<2304, 256, 0, stream>>>(f2, nullptr, pwom, bom, (void*)om);

    nchw_to_nhwc<<<dim3(576, B_, 2), 256, 0, stream>>>(key, value, kT, vT);

    float* out_w = out;
    float* out_v = out + (size_t)B_ * HW_;
    sampler_k<<<(B_ * HW_) / 16, 256, 0, stream>>>(query, kT, vT, om, out_w, out_v);
}